// Round 1
// baseline (261.164 us; speedup 1.0000x reference)
//
#include <hip/hip_runtime.h>
#include <math.h>

#define NUM_EXPERTS 8
#define CAPACITY 320
#define NGROUP 8
#define NTOK 2048
#define HID 2048
#define NTOKENS (NGROUP * NTOK)  // 16384

// Kernel A: router logits + softmax max + argmax.
// Layout: block = 256 threads = 16 teams of 16 lanes; each team handles 2 tokens.
// Lane c of a team covers h = i*64 + c*4 (float4) for i in [0,32) -> full H=2048.
// fp64 accumulation: memory-bound kernel, so the extra VALU cost is hidden, and it
// makes our logits essentially exact -> argmax tie-breaks match the reference.
__global__ __launch_bounds__(256) void router_logits_kernel(
    const float* __restrict__ hs, const float* __restrict__ Wt,
    const float* __restrict__ bias,
    float* __restrict__ out_logits, float* __restrict__ out_pmax,
    int* __restrict__ ws_idx)
{
    const int tid  = threadIdx.x;
    const int c    = tid & 15;          // chunk lane within team
    const int team = tid >> 4;          // 16 teams per block
    const int tokA = blockIdx.x * 32 + team * 2;
    const int tokB = tokA + 1;

    const float4* hsA = (const float4*)(hs + (size_t)tokA * HID);
    const float4* hsB = (const float4*)(hs + (size_t)tokB * HID);
    const float4* Wv  = (const float4*)Wt;

    double accA[NUM_EXPERTS], accB[NUM_EXPERTS];
#pragma unroll
    for (int e = 0; e < NUM_EXPERTS; ++e) { accA[e] = 0.0; accB[e] = 0.0; }

#pragma unroll 4
    for (int i = 0; i < 32; ++i) {
        const int q = i * 16 + c;  // float4 index within a row (H/4 = 512)
        float4 a  = hsA[q];
        float4 d0 = hsB[q];
        double ax = (double)a.x,  ay = (double)a.y,  az = (double)a.z,  aw = (double)a.w;
        double bx = (double)d0.x, by = (double)d0.y, bz = (double)d0.z, bw = (double)d0.w;
#pragma unroll
        for (int e = 0; e < NUM_EXPERTS; ++e) {
            float4 w = Wv[e * (HID / 4) + q];
            double wx = (double)w.x, wy = (double)w.y, wz = (double)w.z, ww = (double)w.w;
            accA[e] += ax * wx + ay * wy + az * wz + aw * ww;
            accB[e] += bx * wx + by * wy + bz * wz + bw * ww;
        }
    }

    // Butterfly reduction over the 4 chunk bits (lanes 0..15 within each team).
#pragma unroll
    for (int m = 1; m < 16; m <<= 1) {
#pragma unroll
        for (int e = 0; e < NUM_EXPERTS; ++e) {
            accA[e] += __shfl_xor(accA[e], m, 64);
            accB[e] += __shfl_xor(accB[e], m, 64);
        }
    }

    if (c == 0) {
        auto emit = [&](const double* acc, int t) {
            float lf[NUM_EXPERTS];
#pragma unroll
            for (int e = 0; e < NUM_EXPERTS; ++e)
                lf[e] = (float)(acc[e] + (double)bias[e]);
            // first-occurrence argmax (matches jnp.argmax tie-break)
            float mx = lf[0];
            int idx = 0;
#pragma unroll
            for (int e = 1; e < NUM_EXPERTS; ++e)
                if (lf[e] > mx) { mx = lf[e]; idx = e; }
            float sum = 0.0f;
#pragma unroll
            for (int e = 0; e < NUM_EXPERTS; ++e)
                sum += expf(lf[e] - mx);
            float4* lp = (float4*)(out_logits + (size_t)t * NUM_EXPERTS);
            lp[0] = make_float4(lf[0], lf[1], lf[2], lf[3]);
            lp[1] = make_float4(lf[4], lf[5], lf[6], lf[7]);
            out_pmax[t] = 1.0f / sum;   // exp(mx-mx)/sum
            ws_idx[t] = idx;
        };
        emit(accA, tokA);
        emit(accB, tokB);
    }
}

// Kernel B: per-group inclusive cumsum of one-hot expert assignment + capacity mask.
// One block per group; thread tid owns tokens [tid*8, tid*8+8). Counts for the 8
// experts are packed 16-bit x8 into 4 uint32 words; Hillis-Steele scan over 256
// threads in LDS; then replay tokens with running counters.
__global__ __launch_bounds__(256) void router_scan_kernel(
    const int* __restrict__ ws_idx, float* __restrict__ out_expert)
{
    __shared__ unsigned sb[4][256];
    const int g    = blockIdx.x;
    const int tid  = threadIdx.x;
    const int tok0 = g * NTOK + tid * 8;

    int idx[8];
#pragma unroll
    for (int j = 0; j < 8; ++j) idx[j] = ws_idx[tok0 + j];

    unsigned lc[4] = {0u, 0u, 0u, 0u};
#pragma unroll
    for (int j = 0; j < 8; ++j)
        lc[idx[j] >> 1] += 1u << ((idx[j] & 1) * 16);

#pragma unroll
    for (int w = 0; w < 4; ++w) sb[w][tid] = lc[w];
    __syncthreads();

    for (int off = 1; off < 256; off <<= 1) {
        unsigned v[4];
#pragma unroll
        for (int w = 0; w < 4; ++w)
            v[w] = (tid >= off) ? sb[w][tid - off] : 0u;
        __syncthreads();
#pragma unroll
        for (int w = 0; w < 4; ++w) sb[w][tid] += v[w];
        __syncthreads();
    }

    // exclusive prefix counts per expert (inclusive - local)
    unsigned run[NUM_EXPERTS];
#pragma unroll
    for (int e = 0; e < NUM_EXPERTS; ++e)
        run[e] = ((sb[e >> 1][tid] - lc[e >> 1]) >> ((e & 1) * 16)) & 0xFFFFu;

#pragma unroll
    for (int j = 0; j < 8; ++j) {
        const int e = idx[j];
        run[e] += 1u;  // inclusive token_priority for this token's expert
        const float keep = (run[e] <= CAPACITY) ? 1.0f : 0.0f;
        float vv[NUM_EXPERTS];
#pragma unroll
        for (int k = 0; k < NUM_EXPERTS; ++k)
            vv[k] = (k == e) ? keep : 0.0f;
        float4* op = (float4*)(out_expert + (size_t)(tok0 + j) * NUM_EXPERTS);
        op[0] = make_float4(vv[0], vv[1], vv[2], vv[3]);
        op[1] = make_float4(vv[4], vv[5], vv[6], vv[7]);
    }
}

extern "C" void kernel_launch(void* const* d_in, const int* in_sizes, int n_in,
                              void* d_out, int out_size, void* d_ws, size_t ws_size,
                              hipStream_t stream) {
    const float* hs = (const float*)d_in[0];
    const float* W  = (const float*)d_in[1];
    const float* b  = (const float*)d_in[2];

    float* out        = (float*)d_out;
    float* out_expert = out;                                      // [G,T,E] one-hot (as float)
    float* out_pmax   = out + (size_t)NTOKENS * NUM_EXPERTS;      // [G,T,1]
    float* out_logits = out_pmax + NTOKENS;                       // [G,T,E]
    int*   ws_idx     = (int*)d_ws;                               // [G*T] argmax expert ids

    router_logits_kernel<<<NTOKENS / 32, 256, 0, stream>>>(hs, W, b,
                                                           out_logits, out_pmax, ws_idx);
    router_scan_kernel<<<NGROUP, 256, 0, stream>>>(ws_idx, out_expert);
}